// Round 5
// baseline (761.326 us; speedup 1.0000x reference)
//
#include <hip/hip_runtime.h>
#include <hip/hip_bf16.h>
#include <cstddef>

#define Bsz 16
#define Ssz 1024
#define Dsz 1024
#define Hn  16
#define HDs 64
#define SCALE_F 0.125f

typedef unsigned short ushort_t;
typedef __bf16 bf16x8 __attribute__((ext_vector_type(8)));
typedef float f32x4 __attribute__((ext_vector_type(4)));
typedef ushort_t u16x4 __attribute__((ext_vector_type(4)));

#define MFMA16(a, b, c) __builtin_amdgcn_mfma_f32_16x16x32_bf16((a), (b), (c), 0, 0, 0)

__device__ inline ushort_t bf16u(float f) {
    __bf16 h = (__bf16)f;
    return __builtin_bit_cast(ushort_t, h);
}

__device__ inline void gld_lds16(const void* g, void* l) {
    __builtin_amdgcn_global_load_lds(
        (const __attribute__((address_space(1))) unsigned int*)g,
        (__attribute__((address_space(3))) unsigned int*)l, 16, 0, 0);
}

// ---------------------------------------------------------------------------
// cast fp32 -> bf16, 8 elems/thread
// ---------------------------------------------------------------------------
__global__ __launch_bounds__(256) void cast_k(const float* __restrict__ in,
                                              ushort_t* __restrict__ o, size_t n)
{
    size_t i = ((size_t)blockIdx.x * 256 + threadIdx.x) * 8;
    if (i >= n) return;
    float4 a = *(const float4*)(in + i);
    float4 b = *(const float4*)(in + i + 4);
    union { ushort_t u[8]; uint4 v; } pk;
    pk.u[0] = bf16u(a.x); pk.u[1] = bf16u(a.y); pk.u[2] = bf16u(a.z); pk.u[3] = bf16u(a.w);
    pk.u[4] = bf16u(b.x); pk.u[5] = bf16u(b.y); pk.u[6] = bf16u(b.z); pk.u[7] = bf16u(b.w);
    *(uint4*)(o + i) = pk.v;
}

// ---------------------------------------------------------------------------
// W[K,N] fp32 -> Wt[N,K] bf16  (32x32 LDS tile transpose)
// ---------------------------------------------------------------------------
__global__ __launch_bounds__(256) void wtrans_k(const float* __restrict__ W,
                                                ushort_t* __restrict__ Wt)
{
    __shared__ float t_[32][33];
    const int tx = threadIdx.x, ty = threadIdx.y;
    const int n0 = blockIdx.x * 32, k0 = blockIdx.y * 32;
    #pragma unroll
    for (int i = 0; i < 4; ++i)
        t_[ty + i * 8][tx] = W[(size_t)(k0 + ty + i * 8) * Dsz + n0 + tx];
    __syncthreads();
    #pragma unroll
    for (int i = 0; i < 4; ++i)
        Wt[(size_t)(n0 + ty + i * 8) * Dsz + k0 + tx] = bf16u(t_[tx][ty + i * 8]);
}

// ---------------------------------------------------------------------------
// C = A[M,K] * Bt[N,K]^T + bias.  bf16 MFMA, 128x128 tile, BK=32.
// MODE 0: fp32 out [M,N] (final projection)
// MODE 1: fused QKV; N=3072; block-uniform tsel = bn>>10 selects target:
//   Q -> Qh[bh][s][64]
//   K -> Kp[bh][s>>4][d>>5][lane=((d>>3)&3)*16+(s&15)][d&7]   (1KB lane-packed)
//   V -> Vp[bh][d>>4][s>>5][lane=((s>>3)&3)*16+(d&15)][s&7]   (1KB lane-packed)
// ---------------------------------------------------------------------------
template <int MODE>
__global__ __launch_bounds__(256) void gemm_bt_k(
    const ushort_t* __restrict__ A, const ushort_t* __restrict__ Bt,
    const float* __restrict__ b0, const float* __restrict__ b1,
    const float* __restrict__ b2,
    void* __restrict__ o0, void* __restrict__ o1, void* __restrict__ o2,
    int M, int N, int K)
{
    __shared__ ushort_t As[128 * 32];
    __shared__ ushort_t Bs[128 * 32];

    const int tid = threadIdx.x;
    const int lane = tid & 63;
    const int wv = tid >> 6;
    const int wr = wv >> 1, wc = wv & 1;
    const int bm = blockIdx.y * 128, bn = blockIdx.x * 128;

    const int srw = tid >> 2;
    const int gc = (tid & 3) ^ ((srw >> 1) & 3);
    const ushort_t* aptr0 = A + (size_t)(bm + srw) * K + gc * 8;
    const ushort_t* aptr1 = A + (size_t)(bm + 64 + srw) * K + gc * 8;
    const ushort_t* bptr0 = Bt + (size_t)(bn + srw) * K + gc * 8;
    const ushort_t* bptr1 = Bt + (size_t)(bn + 64 + srw) * K + gc * 8;
    ushort_t* lA0 = As + tid * 8;
    ushort_t* lA1 = As + 2048 + tid * 8;
    ushort_t* lB0 = Bs + tid * 8;
    ushort_t* lB1 = Bs + 2048 + tid * 8;

    const int am = lane & 15;
    const int rc = lane >> 4;
    const int aslot = rc ^ ((am >> 1) & 3);
    const int rrow_a = wr * 64 + am;
    const int rrow_b = wc * 64 + am;

    f32x4 acc[4][4] = {};

    for (int k0 = 0; k0 < K; k0 += 32) {
        if (k0) __syncthreads();
        gld_lds16(aptr0, lA0); gld_lds16(aptr1, lA1);
        gld_lds16(bptr0, lB0); gld_lds16(bptr1, lB1);
        aptr0 += 32; aptr1 += 32; bptr0 += 32; bptr1 += 32;
        __syncthreads();

        bf16x8 af[4], bfr[4];
        #pragma unroll
        for (int m = 0; m < 4; ++m)
            af[m] = *reinterpret_cast<const bf16x8*>(&As[(rrow_a + m * 16) * 32 + aslot * 8]);
        #pragma unroll
        for (int n = 0; n < 4; ++n)
            bfr[n] = *reinterpret_cast<const bf16x8*>(&Bs[(rrow_b + n * 16) * 32 + aslot * 8]);
        #pragma unroll
        for (int m = 0; m < 4; ++m)
            #pragma unroll
            for (int n = 0; n < 4; ++n)
                acc[m][n] = MFMA16(af[m], bfr[n], acc[m][n]);
    }

    const int erow = rc * 4;

    if constexpr (MODE == 0) {
        float* C = (float*)o0;
        #pragma unroll
        for (int m = 0; m < 4; ++m) {
            #pragma unroll
            for (int n = 0; n < 4; ++n) {
                const int col = bn + wc * 64 + n * 16 + am;
                const float bv = b0[col];
                #pragma unroll
                for (int r = 0; r < 4; ++r) {
                    const int row = bm + wr * 64 + m * 16 + erow + r;
                    C[(size_t)row * N + col] = acc[m][n][r] + bv;
                }
            }
        }
    } else {
        const int tsel = bn >> 10;    // block-uniform (1024 % 128 == 0)
        const float* bias = (tsel == 0) ? b0 : (tsel == 1) ? b1 : b2;
        ushort_t* dst = (ushort_t*)((tsel == 0) ? o0 : (tsel == 1) ? o1 : o2);
        #pragma unroll
        for (int m = 0; m < 4; ++m) {
            const int row0 = bm + wr * 64 + m * 16 + erow;   // +r
            const int b_ = row0 >> 10;
            const int srow0 = row0 & 1023;
            #pragma unroll
            for (int n = 0; n < 4; ++n) {
                const int col = bn + wc * 64 + n * 16 + am;
                const int c1 = col & 1023;
                const int h = c1 >> 6, d = c1 & 63;
                const float bv = bias[c1];
                const size_t hb = ((size_t)(b_ * 16 + h)) << 16;   // *65536
                if (tsel == 0) {
                    // Qh[bh][s][64]
                    #pragma unroll
                    for (int r = 0; r < 4; ++r)
                        dst[hb + (size_t)(srow0 + r) * 64 + d] =
                            bf16u(acc[m][n][r] + bv);
                } else if (tsel == 1) {
                    // Kp: [s>>4][d>>5][((d>>3)&3)*16 + (s&15)][d&7]
                    const size_t base = hb + (size_t)(srow0 >> 4) * 1024
                                      + (d >> 5) * 512
                                      + (((d >> 3) & 3) * 16 + (srow0 & 15)) * 8
                                      + (d & 7);
                    #pragma unroll
                    for (int r = 0; r < 4; ++r)
                        dst[base + r * 8] = bf16u(acc[m][n][r] + bv);
                } else {
                    // Vp: [d>>4][s>>5][((s>>3)&3)*16 + (d&15)][s&7]; 4 consecutive s
                    const size_t base = hb + (size_t)(d >> 4) * 16384
                                      + (srow0 >> 5) * 512
                                      + (((srow0 >> 3) & 3) * 16 + (d & 15)) * 8
                                      + (srow0 & 7);
                    u16x4 pk;
                    pk.x = bf16u(acc[m][n][0] + bv);
                    pk.y = bf16u(acc[m][n][1] + bv);
                    pk.z = bf16u(acc[m][n][2] + bv);
                    pk.w = bf16u(acc[m][n][3] + bv);
                    *(u16x4*)&dst[base] = pk;
                }
            }
        }
    }
}

// ---------------------------------------------------------------------------
// Fused attention v4: QBLK=32, 8 waves (512 thr). Wave wv: q-group g=wv>>2
// (16 rows), key-slice ks=wv&3 (256 keys). Swapped QK^T (P in regs), reg
// softmax, attn write from regs, bf16 P -> LDS (XOR swizzle) -> PV MFMA with
// 4-deep V prefetch ring. Bijective XCD swizzle: each head's 32 q-blocks on
// one XCD's L2.
// ---------------------------------------------------------------------------
__global__ __launch_bounds__(512, 4) void attn_fused_k(
    const ushort_t* __restrict__ Qh, const ushort_t* __restrict__ Kp,
    const ushort_t* __restrict__ Vp, float* __restrict__ attn,
    ushort_t* __restrict__ ctx)
{
    __shared__ ushort_t Pl[32 * 1024];   // [q][k] bf16, byte^=(q&7)<<4 swizzle
    __shared__ float smax[2][4][16];
    __shared__ float ssum[2][4][16];
    __shared__ float invb[2][16];

    const int tid = threadIdx.x;
    const int lane = tid & 63;
    const int wv = tid >> 6;        // 0..7
    const int am = lane & 15;
    const int ak = lane >> 4;
    const int g  = wv >> 2;         // q-group (16 rows)
    const int ks = wv & 3;          // key slice (256 keys)
    const int kb = ks * 256;

    const int wg = blockIdx.x;                     // 8192 blocks
    const int swz = (wg & 7) * 1024 + (wg >> 3);   // bijective XCD swizzle
    const int bh = swz >> 5;
    const int q0 = (swz & 31) << 5;
    const int b = bh >> 4, h = bh & 15;
    const size_t hb = (size_t)bh << 16;            // *65536

    // ---- phase 1: scores^T via mfma(K, Q); lane holds q=am, 64 keys ----
    const ushort_t* qptr = Qh + hb + (size_t)(q0 + g * 16 + am) * 64 + ak * 8;
    const bf16x8 qf0 = *(const bf16x8*)qptr;
    const bf16x8 qf1 = *(const bf16x8*)(qptr + 32);

    f32x4 acc[16];
    #pragma unroll
    for (int n = 0; n < 16; ++n) acc[n] = (f32x4){0.f, 0.f, 0.f, 0.f};

    const ushort_t* kt = Kp + hb + (size_t)(ks * 16) * 1024 + lane * 8;
    __builtin_amdgcn_s_setprio(1);
    #pragma unroll
    for (int n = 0; n < 16; ++n) {
        const bf16x8 kf0 = *(const bf16x8*)(kt + n * 1024);
        const bf16x8 kf1 = *(const bf16x8*)(kt + n * 1024 + 512);
        acc[n] = MFMA16(kf0, qf0, acc[n]);
        acc[n] = MFMA16(kf1, qf1, acc[n]);
    }
    __builtin_amdgcn_s_setprio(0);

    // ---- phase 2: softmax stats in-register ----
    float m = -1e30f;
    #pragma unroll
    for (int n = 0; n < 16; ++n)
        #pragma unroll
        for (int r = 0; r < 4; ++r) m = fmaxf(m, acc[n][r]);
    m = fmaxf(m, __shfl_xor(m, 16));
    m = fmaxf(m, __shfl_xor(m, 32));
    if (ak == 0) smax[g][ks][am] = m;
    __syncthreads();
    m = fmaxf(fmaxf(smax[g][0][am], smax[g][1][am]),
              fmaxf(smax[g][2][am], smax[g][3][am]));

    float s = 0.f;
    #pragma unroll
    for (int n = 0; n < 16; ++n)
        #pragma unroll
        for (int r = 0; r < 4; ++r) {
            const float e = __expf((acc[n][r] - m) * SCALE_F);
            acc[n][r] = e;
            s += e;
        }
    s += __shfl_xor(s, 16);
    s += __shfl_xor(s, 32);
    if (ak == 0) ssum[g][ks][am] = s;

    // ---- phase 3a: P (unnormalized e) -> LDS bf16, swizzled ----
    char* prow = (char*)Pl + (g * 16 + am) * 2048;
    const int xr = (am & 7) << 4;
    #pragma unroll
    for (int n = 0; n < 16; ++n) {
        u16x4 pk;
        pk.x = bf16u(acc[n][0]); pk.y = bf16u(acc[n][1]);
        pk.z = bf16u(acc[n][2]); pk.w = bf16u(acc[n][3]);
        *(u16x4*)(prow + (((kb + n * 16 + ak * 4) * 2) ^ xr)) = pk;
    }
    __syncthreads();

    const float inv = 1.0f / (ssum[g][0][am] + ssum[g][1][am] +
                              ssum[g][2][am] + ssum[g][3][am]);
    if (ks == 0 && ak == 0) invb[g][am] = inv;

    // ---- phase 3b: write normalized attn from registers ----
    float* aout = attn + ((size_t)bh * Ssz + q0 + g * 16 + am) * Ssz + kb + ak * 4;
    #pragma unroll
    for (int n = 0; n < 16; ++n) {
        float4 v;
        v.x = acc[n][0] * inv; v.y = acc[n][1] * inv;
        v.z = acc[n][2] * inv; v.w = acc[n][3] * inv;
        *(float4*)(aout + n * 16) = v;
    }
    __syncthreads();

    // ---- phase 4: PV. wave -> q-group g, d slice [ks*16,+16);
    //      C row q = ak*4+r, col d = am. 4-deep V prefetch ring. ----
    f32x4 po = {0.f, 0.f, 0.f, 0.f};
    const ushort_t* vt = Vp + hb + (size_t)ks * 16384 + lane * 8;
    bf16x8 v0 = *(const bf16x8*)(vt);
    bf16x8 v1 = *(const bf16x8*)(vt + 512);
    bf16x8 v2 = *(const bf16x8*)(vt + 1024);
    bf16x8 v3 = *(const bf16x8*)(vt + 1536);
    __builtin_amdgcn_s_setprio(1);
    #pragma unroll
    for (int w = 0; w < 32; w += 4) {
        const bf16x8 p0 = *(const bf16x8*)(prow + (((w + 0) * 64 + ak * 16) ^ xr));
        const bf16x8 p1 = *(const bf16x8*)(prow + (((w + 1) * 64 + ak * 16) ^ xr));
        const bf16x8 p2 = *(const bf16x8*)(prow + (((w + 2) * 64 + ak * 16) ^ xr));
        const bf16x8 p3 = *(const bf16x8*)(prow + (((w + 3) * 64 + ak * 16) ^ xr));
        po = MFMA16(p0, v0, po);
        if (w + 4 < 32) v0 = *(const bf16x8*)(vt + (w + 4) * 512);
        po = MFMA16(p1, v1, po);
        if (w + 5 < 32) v1 = *(const bf16x8*)(vt + (w + 5) * 512);
        po = MFMA16(p2, v2, po);
        if (w + 6 < 32) v2 = *(const bf16x8*)(vt + (w + 6) * 512);
        po = MFMA16(p3, v3, po);
        if (w + 7 < 32) v3 = *(const bf16x8*)(vt + (w + 7) * 512);
    }
    __builtin_amdgcn_s_setprio(0);
    #pragma unroll
    for (int r = 0; r < 4; ++r) {
        const float v = po[r] * invb[g][ak * 4 + r];
        ctx[((size_t)b * Ssz + q0 + g * 16 + ak * 4 + r) * Dsz + h * HDs + ks * 16 + am]
            = bf16u(v);
    }
}

// ---------------------------------------------------------------------------
extern "C" void kernel_launch(void* const* d_in, const int* in_sizes, int n_in,
                              void* d_out, int out_size, void* d_ws, size_t ws_size,
                              hipStream_t stream)
{
    const float* x  = (const float*)d_in[0];
    const float* Wq = (const float*)d_in[1];
    const float* bq = (const float*)d_in[2];
    const float* Wk = (const float*)d_in[3];
    const float* bk = (const float*)d_in[4];
    const float* Wv = (const float*)d_in[5];
    const float* bv = (const float*)d_in[6];
    const float* Wo = (const float*)d_in[7];
    const float* bo = (const float*)d_in[8];

    const size_t BSD = (size_t)Bsz * Ssz * Dsz;   // 16.7M
    const size_t WSZ = (size_t)Dsz * Dsz;         // 1M

    float* outp = (float*)d_out;                  // [B,S,D] fp32
    float* attn = outp + BSD;                     // [B,H,S,S] fp32

    ushort_t* xbf  = (ushort_t*)d_ws;
    ushort_t* Qh   = xbf + BSD;
    ushort_t* Kp   = Qh + BSD;
    ushort_t* Vp   = Kp + BSD;
    ushort_t* ctxb = Vp + BSD;
    ushort_t* Wqkv = ctxb + BSD;                  // [3072][1024] = Wq^T|Wk^T|Wv^T
    ushort_t* Wot  = Wqkv + 3 * WSZ;

    const int M = Bsz * Ssz;                      // 16384

    cast_k<<<dim3((unsigned)(BSD / 2048)), 256, 0, stream>>>(x, xbf, BSD);

    dim3 tblk(32, 8);
    dim3 tgrd(32, 32);
    wtrans_k<<<tgrd, tblk, 0, stream>>>(Wq, Wqkv);
    wtrans_k<<<tgrd, tblk, 0, stream>>>(Wk, Wqkv + WSZ);
    wtrans_k<<<tgrd, tblk, 0, stream>>>(Wv, Wqkv + 2 * WSZ);
    wtrans_k<<<tgrd, tblk, 0, stream>>>(Wo, Wot);

    // fused QKV GEMM: N=3072
    gemm_bt_k<1><<<dim3(24, 128), 256, 0, stream>>>(
        xbf, Wqkv, bq, bk, bv, Qh, Kp, Vp, M, 3072, Dsz);

    attn_fused_k<<<dim3(8192), 512, 0, stream>>>(Qh, Kp, Vp, attn, ctxb);

    gemm_bt_k<0><<<dim3(8, 128), 256, 0, stream>>>(
        ctxb, Wot, bo, nullptr, nullptr, outp, nullptr, nullptr, M, Dsz, Dsz);
}

// Round 7
// 549.981 us; speedup vs baseline: 1.3843x; 1.3843x over previous
//
#include <hip/hip_runtime.h>
#include <hip/hip_bf16.h>
#include <cstddef>

#define Bsz 16
#define Ssz 1024
#define Dsz 1024
#define Hn  16
#define HDs 64
#define SCALE_F 0.125f

typedef unsigned short ushort_t;
typedef __bf16 bf16x8 __attribute__((ext_vector_type(8)));
typedef float f32x4 __attribute__((ext_vector_type(4)));
typedef ushort_t u16x4 __attribute__((ext_vector_type(4)));

#define MFMA16(a, b, c) __builtin_amdgcn_mfma_f32_16x16x32_bf16((a), (b), (c), 0, 0, 0)

__device__ inline ushort_t bf16u(float f) {
    __bf16 h = (__bf16)f;
    return __builtin_bit_cast(ushort_t, h);
}

__device__ inline void gld_lds16(const void* g, void* l) {
    __builtin_amdgcn_global_load_lds(
        (const __attribute__((address_space(1))) unsigned int*)g,
        (__attribute__((address_space(3))) unsigned int*)l, 16, 0, 0);
}

// ---------------------------------------------------------------------------
// cast fp32 -> bf16, 8 elems/thread
// ---------------------------------------------------------------------------
__global__ __launch_bounds__(256) void cast_k(const float* __restrict__ in,
                                              ushort_t* __restrict__ o, size_t n)
{
    size_t i = ((size_t)blockIdx.x * 256 + threadIdx.x) * 8;
    if (i >= n) return;
    float4 a = *(const float4*)(in + i);
    float4 b = *(const float4*)(in + i + 4);
    union { ushort_t u[8]; uint4 v; } pk;
    pk.u[0] = bf16u(a.x); pk.u[1] = bf16u(a.y); pk.u[2] = bf16u(a.z); pk.u[3] = bf16u(a.w);
    pk.u[4] = bf16u(b.x); pk.u[5] = bf16u(b.y); pk.u[6] = bf16u(b.z); pk.u[7] = bf16u(b.w);
    *(uint4*)(o + i) = pk.v;
}

// ---------------------------------------------------------------------------
// W[K,N] fp32 -> Wt[N,K] bf16  (32x32 LDS tile transpose)
// ---------------------------------------------------------------------------
__global__ __launch_bounds__(256) void wtrans_k(const float* __restrict__ W,
                                                ushort_t* __restrict__ Wt)
{
    __shared__ float t_[32][33];
    const int tx = threadIdx.x, ty = threadIdx.y;
    const int n0 = blockIdx.x * 32, k0 = blockIdx.y * 32;
    #pragma unroll
    for (int i = 0; i < 4; ++i)
        t_[ty + i * 8][tx] = W[(size_t)(k0 + ty + i * 8) * Dsz + n0 + tx];
    __syncthreads();
    #pragma unroll
    for (int i = 0; i < 4; ++i)
        Wt[(size_t)(n0 + ty + i * 8) * Dsz + k0 + tx] = bf16u(t_[tx][ty + i * 8]);
}

// ---------------------------------------------------------------------------
// C = A[M,K] * Bt[N,K]^T + bias.  bf16 MFMA, 128x128 tile, BK=32.
// MODE 0: fp32 out [M,N] (final projection)
// MODE 1: fused QKV; N=3072; block-uniform tsel = bn>>10 selects target:
//   Q -> Qh[bh][s][64]
//   K -> Kp[bh][s>>4][d>>5][lane=((d>>3)&3)*16+(s&15)][d&7]   (1KB lane-packed)
//   V -> Vp[bh][d>>4][s>>5][lane=((s>>3)&3)*16+(d&15)][s&7]   (1KB lane-packed)
// ---------------------------------------------------------------------------
template <int MODE>
__global__ __launch_bounds__(256) void gemm_bt_k(
    const ushort_t* __restrict__ A, const ushort_t* __restrict__ Bt,
    const float* __restrict__ b0, const float* __restrict__ b1,
    const float* __restrict__ b2,
    void* __restrict__ o0, void* __restrict__ o1, void* __restrict__ o2,
    int M, int N, int K)
{
    __shared__ ushort_t As[128 * 32];
    __shared__ ushort_t Bs[128 * 32];

    const int tid = threadIdx.x;
    const int lane = tid & 63;
    const int wv = tid >> 6;
    const int wr = wv >> 1, wc = wv & 1;
    const int bm = blockIdx.y * 128, bn = blockIdx.x * 128;

    const int srw = tid >> 2;
    const int gc = (tid & 3) ^ ((srw >> 1) & 3);
    const ushort_t* aptr0 = A + (size_t)(bm + srw) * K + gc * 8;
    const ushort_t* aptr1 = A + (size_t)(bm + 64 + srw) * K + gc * 8;
    const ushort_t* bptr0 = Bt + (size_t)(bn + srw) * K + gc * 8;
    const ushort_t* bptr1 = Bt + (size_t)(bn + 64 + srw) * K + gc * 8;
    ushort_t* lA0 = As + tid * 8;
    ushort_t* lA1 = As + 2048 + tid * 8;
    ushort_t* lB0 = Bs + tid * 8;
    ushort_t* lB1 = Bs + 2048 + tid * 8;

    const int am = lane & 15;
    const int rc = lane >> 4;
    const int aslot = rc ^ ((am >> 1) & 3);
    const int rrow_a = wr * 64 + am;
    const int rrow_b = wc * 64 + am;

    f32x4 acc[4][4] = {};

    for (int k0 = 0; k0 < K; k0 += 32) {
        if (k0) __syncthreads();
        gld_lds16(aptr0, lA0); gld_lds16(aptr1, lA1);
        gld_lds16(bptr0, lB0); gld_lds16(bptr1, lB1);
        aptr0 += 32; aptr1 += 32; bptr0 += 32; bptr1 += 32;
        __syncthreads();

        bf16x8 af[4], bfr[4];
        #pragma unroll
        for (int m = 0; m < 4; ++m)
            af[m] = *reinterpret_cast<const bf16x8*>(&As[(rrow_a + m * 16) * 32 + aslot * 8]);
        #pragma unroll
        for (int n = 0; n < 4; ++n)
            bfr[n] = *reinterpret_cast<const bf16x8*>(&Bs[(rrow_b + n * 16) * 32 + aslot * 8]);
        #pragma unroll
        for (int m = 0; m < 4; ++m)
            #pragma unroll
            for (int n = 0; n < 4; ++n)
                acc[m][n] = MFMA16(af[m], bfr[n], acc[m][n]);
    }

    const int erow = rc * 4;

    if constexpr (MODE == 0) {
        float* C = (float*)o0;
        #pragma unroll
        for (int m = 0; m < 4; ++m) {
            #pragma unroll
            for (int n = 0; n < 4; ++n) {
                const int col = bn + wc * 64 + n * 16 + am;
                const float bv = b0[col];
                #pragma unroll
                for (int r = 0; r < 4; ++r) {
                    const int row = bm + wr * 64 + m * 16 + erow + r;
                    C[(size_t)row * N + col] = acc[m][n][r] + bv;
                }
            }
        }
    } else {
        const int tsel = bn >> 10;    // block-uniform (1024 % 128 == 0)
        const float* bias = (tsel == 0) ? b0 : (tsel == 1) ? b1 : b2;
        ushort_t* dst = (ushort_t*)((tsel == 0) ? o0 : (tsel == 1) ? o1 : o2);
        #pragma unroll
        for (int m = 0; m < 4; ++m) {
            const int row0 = bm + wr * 64 + m * 16 + erow;   // +r
            const int b_ = row0 >> 10;
            const int srow0 = row0 & 1023;
            #pragma unroll
            for (int n = 0; n < 4; ++n) {
                const int col = bn + wc * 64 + n * 16 + am;
                const int c1 = col & 1023;
                const int h = c1 >> 6, d = c1 & 63;
                const float bv = bias[c1];
                const size_t hb = ((size_t)(b_ * 16 + h)) << 16;   // *65536
                if (tsel == 0) {
                    // Qh[bh][s][64]
                    #pragma unroll
                    for (int r = 0; r < 4; ++r)
                        dst[hb + (size_t)(srow0 + r) * 64 + d] =
                            bf16u(acc[m][n][r] + bv);
                } else if (tsel == 1) {
                    // Kp: [s>>4][d>>5][((d>>3)&3)*16 + (s&15)][d&7]
                    const size_t base = hb + (size_t)(srow0 >> 4) * 1024
                                      + (d >> 5) * 512
                                      + (((d >> 3) & 3) * 16 + (srow0 & 15)) * 8
                                      + (d & 7);
                    #pragma unroll
                    for (int r = 0; r < 4; ++r)
                        dst[base + r * 8] = bf16u(acc[m][n][r] + bv);
                } else {
                    // Vp: [d>>4][s>>5][((s>>3)&3)*16 + (d&15)][s&7]; 4 consecutive s
                    const size_t base = hb + (size_t)(d >> 4) * 16384
                                      + (srow0 >> 5) * 512
                                      + (((srow0 >> 3) & 3) * 16 + (d & 15)) * 8
                                      + (srow0 & 7);
                    u16x4 pk;
                    pk.x = bf16u(acc[m][n][0] + bv);
                    pk.y = bf16u(acc[m][n][1] + bv);
                    pk.z = bf16u(acc[m][n][2] + bv);
                    pk.w = bf16u(acc[m][n][3] + bv);
                    *(u16x4*)&dst[base] = pk;
                }
            }
        }
    }
}

// ---------------------------------------------------------------------------
// Fused attention v5b: QBLK=16, 4 waves. Swapped QK^T (P in regs), NO-MAX
// softmax (clamped exp; normalization-invariant), 2 barriers total, attn
// nontemporal stores (clang vector type) overlapped with PV MFMA, 4-deep V
// prefetch ring. Bijective XCD swizzle keeps each head on one XCD's L2.
// ---------------------------------------------------------------------------
__global__ __launch_bounds__(256, 4) void attn_fused_k(
    const ushort_t* __restrict__ Qh, const ushort_t* __restrict__ Kp,
    const ushort_t* __restrict__ Vp, float* __restrict__ attn,
    ushort_t* __restrict__ ctx)
{
    __shared__ ushort_t Pl[16 * 1024];   // [q][k] bf16, byte^=(q&7)<<4 swizzle
    __shared__ float ssum[4][16];
    __shared__ float invb[16];

    const int tid = threadIdx.x;
    const int lane = tid & 63;
    const int wv = tid >> 6;
    const int am = lane & 15;
    const int ak = lane >> 4;
    const int kb = wv * 256;

    const int wg = blockIdx.x;                    // 16384 blocks
    const int swz = (wg & 7) * 2048 + (wg >> 3);  // bijective XCD swizzle
    const int bh = swz >> 6;
    const int q0 = (swz & 63) << 4;
    const int b = bh >> 4, h = bh & 15;
    const size_t hb = (size_t)bh << 16;           // *65536

    // ---- phase 1: scores^T via mfma(K, Q); lane holds q=am, 64 keys ----
    const ushort_t* qptr = Qh + hb + (size_t)(q0 + am) * 64 + ak * 8;
    const bf16x8 qf0 = *(const bf16x8*)qptr;
    const bf16x8 qf1 = *(const bf16x8*)(qptr + 32);

    f32x4 acc[16];
    #pragma unroll
    for (int n = 0; n < 16; ++n) acc[n] = (f32x4){0.f, 0.f, 0.f, 0.f};

    const ushort_t* kt = Kp + hb + (size_t)(wv * 16) * 1024 + lane * 8;
    __builtin_amdgcn_s_setprio(1);
    #pragma unroll
    for (int n = 0; n < 16; ++n) {
        const bf16x8 kf0 = *(const bf16x8*)(kt + n * 1024);
        const bf16x8 kf1 = *(const bf16x8*)(kt + n * 1024 + 512);
        acc[n] = MFMA16(kf0, qf0, acc[n]);
        acc[n] = MFMA16(kf1, qf1, acc[n]);
    }
    __builtin_amdgcn_s_setprio(0);

    // ---- phase 2: exp (no max pass; arg clamped; normalization-invariant) ----
    float s = 0.f;
    #pragma unroll
    for (int n = 0; n < 16; ++n)
        #pragma unroll
        for (int r = 0; r < 4; ++r) {
            const float e = __expf(fminf(acc[n][r] * SCALE_F, 60.0f));
            acc[n][r] = e;
            s += e;
        }
    s += __shfl_xor(s, 16);
    s += __shfl_xor(s, 32);
    if (ak == 0) ssum[wv][am] = s;

    // ---- phase 3a: P (unnormalized e) -> LDS bf16, swizzled ----
    char* prow = (char*)Pl + am * 2048;
    const int xr = (am & 7) << 4;
    #pragma unroll
    for (int n = 0; n < 16; ++n) {
        u16x4 pk;
        pk.x = bf16u(acc[n][0]); pk.y = bf16u(acc[n][1]);
        pk.z = bf16u(acc[n][2]); pk.w = bf16u(acc[n][3]);
        *(u16x4*)(prow + (((kb + n * 16 + ak * 4) * 2) ^ xr)) = pk;
    }
    __syncthreads();   // P + ssum visible

    const float inv = 1.0f / (ssum[0][am] + ssum[1][am] + ssum[2][am] + ssum[3][am]);
    if (wv == 0 && ak == 0) invb[am] = inv;

    // ---- phase 3b: normalized attn from regs (nontemporal, overlaps PV) ----
    float* aout = attn + ((size_t)bh * Ssz + q0 + am) * Ssz + kb + ak * 4;
    #pragma unroll
    for (int n = 0; n < 16; ++n) {
        f32x4 v;
        v[0] = acc[n][0] * inv; v[1] = acc[n][1] * inv;
        v[2] = acc[n][2] * inv; v[3] = acc[n][3] * inv;
        __builtin_nontemporal_store(v, (f32x4*)(aout + n * 16));
    }

    // ---- phase 4: PV. wave wv -> d slice [wv*16,+16); C row q=ak*4+r, col
    //      d=am. 4-deep V prefetch ring; no barrier before (P safe above). ----
    f32x4 po = {0.f, 0.f, 0.f, 0.f};
    const ushort_t* vt = Vp + hb + (size_t)wv * 16384 + lane * 8;
    bf16x8 v0 = *(const bf16x8*)(vt);
    bf16x8 v1 = *(const bf16x8*)(vt + 512);
    bf16x8 v2 = *(const bf16x8*)(vt + 1024);
    bf16x8 v3 = *(const bf16x8*)(vt + 1536);
    __builtin_amdgcn_s_setprio(1);
    #pragma unroll
    for (int w = 0; w < 32; w += 4) {
        const bf16x8 p0 = *(const bf16x8*)(prow + (((w + 0) * 64 + ak * 16) ^ xr));
        const bf16x8 p1 = *(const bf16x8*)(prow + (((w + 1) * 64 + ak * 16) ^ xr));
        const bf16x8 p2 = *(const bf16x8*)(prow + (((w + 2) * 64 + ak * 16) ^ xr));
        const bf16x8 p3 = *(const bf16x8*)(prow + (((w + 3) * 64 + ak * 16) ^ xr));
        po = MFMA16(p0, v0, po);
        if (w + 4 < 32) v0 = *(const bf16x8*)(vt + (w + 4) * 512);
        po = MFMA16(p1, v1, po);
        if (w + 5 < 32) v1 = *(const bf16x8*)(vt + (w + 5) * 512);
        po = MFMA16(p2, v2, po);
        if (w + 6 < 32) v2 = *(const bf16x8*)(vt + (w + 6) * 512);
        po = MFMA16(p3, v3, po);
        if (w + 7 < 32) v3 = *(const bf16x8*)(vt + (w + 7) * 512);
    }
    __builtin_amdgcn_s_setprio(0);
    __syncthreads();   // invb visible

    #pragma unroll
    for (int r = 0; r < 4; ++r) {
        const float v = po[r] * invb[ak * 4 + r];
        ctx[((size_t)b * Ssz + q0 + ak * 4 + r) * Dsz + h * HDs + wv * 16 + am] = bf16u(v);
    }
}

// ---------------------------------------------------------------------------
extern "C" void kernel_launch(void* const* d_in, const int* in_sizes, int n_in,
                              void* d_out, int out_size, void* d_ws, size_t ws_size,
                              hipStream_t stream)
{
    const float* x  = (const float*)d_in[0];
    const float* Wq = (const float*)d_in[1];
    const float* bq = (const float*)d_in[2];
    const float* Wk = (const float*)d_in[3];
    const float* bk = (const float*)d_in[4];
    const float* Wv = (const float*)d_in[5];
    const float* bv = (const float*)d_in[6];
    const float* Wo = (const float*)d_in[7];
    const float* bo = (const float*)d_in[8];

    const size_t BSD = (size_t)Bsz * Ssz * Dsz;   // 16.7M
    const size_t WSZ = (size_t)Dsz * Dsz;         // 1M

    float* outp = (float*)d_out;                  // [B,S,D] fp32
    float* attn = outp + BSD;                     // [B,H,S,S] fp32

    ushort_t* xbf  = (ushort_t*)d_ws;
    ushort_t* Qh   = xbf + BSD;
    ushort_t* Kp   = Qh + BSD;
    ushort_t* Vp   = Kp + BSD;
    ushort_t* ctxb = Vp + BSD;
    ushort_t* Wqkv = ctxb + BSD;                  // [3072][1024] = Wq^T|Wk^T|Wv^T
    ushort_t* Wot  = Wqkv + 3 * WSZ;

    const int M = Bsz * Ssz;                      // 16384

    cast_k<<<dim3((unsigned)(BSD / 2048)), 256, 0, stream>>>(x, xbf, BSD);

    dim3 tblk(32, 8);
    dim3 tgrd(32, 32);
    wtrans_k<<<tgrd, tblk, 0, stream>>>(Wq, Wqkv);
    wtrans_k<<<tgrd, tblk, 0, stream>>>(Wk, Wqkv + WSZ);
    wtrans_k<<<tgrd, tblk, 0, stream>>>(Wv, Wqkv + 2 * WSZ);
    wtrans_k<<<tgrd, tblk, 0, stream>>>(Wo, Wot);

    // fused QKV GEMM: N=3072
    gemm_bt_k<1><<<dim3(24, 128), 256, 0, stream>>>(
        xbf, Wqkv, bq, bk, bv, Qh, Kp, Vp, M, 3072, Dsz);

    attn_fused_k<<<dim3(16384), 256, 0, stream>>>(Qh, Kp, Vp, attn, ctxb);

    gemm_bt_k<0><<<dim3(8, 128), 256, 0, stream>>>(
        ctxb, Wot, bo, nullptr, nullptr, outp, nullptr, nullptr, M, Dsz, Dsz);
}

// Round 8
// 542.432 us; speedup vs baseline: 1.4035x; 1.0139x over previous
//
#include <hip/hip_runtime.h>
#include <hip/hip_bf16.h>
#include <cstddef>

#define Bsz 16
#define Ssz 1024
#define Dsz 1024
#define Hn  16
#define HDs 64
#define SCALE_F 0.125f

typedef unsigned short ushort_t;
typedef __bf16 bf16x8 __attribute__((ext_vector_type(8)));
typedef float f32x4 __attribute__((ext_vector_type(4)));
typedef ushort_t u16x4 __attribute__((ext_vector_type(4)));
typedef ushort_t u16x8 __attribute__((ext_vector_type(8)));

#define MFMA16(a, b, c) __builtin_amdgcn_mfma_f32_16x16x32_bf16((a), (b), (c), 0, 0, 0)

__device__ inline ushort_t bf16u(float f) {
    __bf16 h = (__bf16)f;
    return __builtin_bit_cast(ushort_t, h);
}

__device__ inline void gld_lds16(const void* g, void* l) {
    __builtin_amdgcn_global_load_lds(
        (const __attribute__((address_space(1))) unsigned int*)g,
        (__attribute__((address_space(3))) unsigned int*)l, 16, 0, 0);
}

// ---------------------------------------------------------------------------
// cast fp32 -> bf16, 8 elems/thread
// ---------------------------------------------------------------------------
__global__ __launch_bounds__(256) void cast_k(const float* __restrict__ in,
                                              ushort_t* __restrict__ o, size_t n)
{
    size_t i = ((size_t)blockIdx.x * 256 + threadIdx.x) * 8;
    if (i >= n) return;
    float4 a = *(const float4*)(in + i);
    float4 b = *(const float4*)(in + i + 4);
    union { ushort_t u[8]; uint4 v; } pk;
    pk.u[0] = bf16u(a.x); pk.u[1] = bf16u(a.y); pk.u[2] = bf16u(a.z); pk.u[3] = bf16u(a.w);
    pk.u[4] = bf16u(b.x); pk.u[5] = bf16u(b.y); pk.u[6] = bf16u(b.z); pk.u[7] = bf16u(b.w);
    *(uint4*)(o + i) = pk.v;
}

// ---------------------------------------------------------------------------
// W[K,N] fp32 -> Wt[N,K] bf16, all 4 weights in one launch (z selects)
// ---------------------------------------------------------------------------
__global__ __launch_bounds__(256) void wtrans_k(
    const float* __restrict__ W0, const float* __restrict__ W1,
    const float* __restrict__ W2, const float* __restrict__ W3,
    ushort_t* __restrict__ T012, ushort_t* __restrict__ T3)
{
    __shared__ float t_[32][33];
    const int tx = threadIdx.x, ty = threadIdx.y;
    const int n0 = blockIdx.x * 32, k0 = blockIdx.y * 32;
    const int z = blockIdx.z;
    const float* W = (z == 0) ? W0 : (z == 1) ? W1 : (z == 2) ? W2 : W3;
    ushort_t* Wt = (z < 3) ? (T012 + (size_t)z * Dsz * Dsz) : T3;
    #pragma unroll
    for (int i = 0; i < 4; ++i)
        t_[ty + i * 8][tx] = W[(size_t)(k0 + ty + i * 8) * Dsz + n0 + tx];
    __syncthreads();
    #pragma unroll
    for (int i = 0; i < 4; ++i)
        Wt[(size_t)(n0 + ty + i * 8) * Dsz + k0 + tx] = bf16u(t_[tx][ty + i * 8]);
}

// ---------------------------------------------------------------------------
// C = A[M,K] * Bt[N,K]^T + bias.  bf16 MFMA, 128x128 tile, BK=32.
// MODE 0: fp32 out [M,N] (final projection)
// MODE 1: fused QKV; N=3072; block-uniform tsel = bn>>10 selects target:
//   Q -> Qh[bh][s][64]   (value pre-scaled by SCALE_F)
//   K -> Kp[bh][s>>4][d>>5][((d>>3)&3)*16+(s&15)][d&7]   (1KB lane-packed)
//   V -> Vp[bh][d>>4][s>>5][((s>>3)&3)*16+(d&15)][s&7]   (1KB lane-packed)
// Q/K epilogue goes through an LDS [c][s] transpose (pad 132) so all global
// stores are 16B d-runs; V stores s-runs directly (8B).
// ---------------------------------------------------------------------------
template <int MODE>
__global__ __launch_bounds__(256) void gemm_bt_k(
    const ushort_t* __restrict__ A, const ushort_t* __restrict__ Bt,
    const float* __restrict__ b0, const float* __restrict__ b1,
    const float* __restrict__ b2,
    void* __restrict__ o0, void* __restrict__ o1, void* __restrict__ o2,
    int M, int N, int K)
{
    __shared__ ushort_t shmem[MODE == 1 ? 128 * 132 : 128 * 64];
    ushort_t* As = shmem;                 // 128*32
    ushort_t* Bs = shmem + 128 * 32;      // 128*32

    const int tid = threadIdx.x;
    const int lane = tid & 63;
    const int wv = tid >> 6;
    const int wr = wv >> 1, wc = wv & 1;
    const int bm = blockIdx.y * 128, bn = blockIdx.x * 128;

    const int srw = tid >> 2;
    const int gc = (tid & 3) ^ ((srw >> 1) & 3);
    const ushort_t* aptr0 = A + (size_t)(bm + srw) * K + gc * 8;
    const ushort_t* aptr1 = A + (size_t)(bm + 64 + srw) * K + gc * 8;
    const ushort_t* bptr0 = Bt + (size_t)(bn + srw) * K + gc * 8;
    const ushort_t* bptr1 = Bt + (size_t)(bn + 64 + srw) * K + gc * 8;
    ushort_t* lA0 = As + tid * 8;
    ushort_t* lA1 = As + 2048 + tid * 8;
    ushort_t* lB0 = Bs + tid * 8;
    ushort_t* lB1 = Bs + 2048 + tid * 8;

    const int am = lane & 15;
    const int rc = lane >> 4;
    const int aslot = rc ^ ((am >> 1) & 3);
    const int rrow_a = wr * 64 + am;
    const int rrow_b = wc * 64 + am;

    f32x4 acc[4][4] = {};

    for (int k0 = 0; k0 < K; k0 += 32) {
        if (k0) __syncthreads();
        gld_lds16(aptr0, lA0); gld_lds16(aptr1, lA1);
        gld_lds16(bptr0, lB0); gld_lds16(bptr1, lB1);
        aptr0 += 32; aptr1 += 32; bptr0 += 32; bptr1 += 32;
        __syncthreads();

        bf16x8 af[4], bfr[4];
        #pragma unroll
        for (int m = 0; m < 4; ++m)
            af[m] = *reinterpret_cast<const bf16x8*>(&As[(rrow_a + m * 16) * 32 + aslot * 8]);
        #pragma unroll
        for (int n = 0; n < 4; ++n)
            bfr[n] = *reinterpret_cast<const bf16x8*>(&Bs[(rrow_b + n * 16) * 32 + aslot * 8]);
        #pragma unroll
        for (int m = 0; m < 4; ++m)
            #pragma unroll
            for (int n = 0; n < 4; ++n)
                acc[m][n] = MFMA16(af[m], bfr[n], acc[m][n]);
    }

    const int erow = rc * 4;

    if constexpr (MODE == 0) {
        float* C = (float*)o0;
        #pragma unroll
        for (int m = 0; m < 4; ++m) {
            #pragma unroll
            for (int n = 0; n < 4; ++n) {
                const int col = bn + wc * 64 + n * 16 + am;
                const float bv = b0[col];
                #pragma unroll
                for (int r = 0; r < 4; ++r) {
                    const int row = bm + wr * 64 + m * 16 + erow + r;
                    C[(size_t)row * N + col] = acc[m][n][r] + bv;
                }
            }
        }
    } else {
        const int tsel = bn >> 10;    // block-uniform (1024 % 128 == 0)
        const float* bias = (tsel == 0) ? b0 : (tsel == 1) ? b1 : b2;
        ushort_t* dst = (ushort_t*)((tsel == 0) ? o0 : (tsel == 1) ? o1 : o2);
        const int bnm = bn & 1023;

        if (tsel == 2) {
            // V: direct s-run stores (8B), layout wants s-contiguous
            #pragma unroll
            for (int m = 0; m < 4; ++m) {
                const int row0 = bm + wr * 64 + m * 16 + erow;
                const int b_ = row0 >> 10;
                const int srow0 = row0 & 1023;
                #pragma unroll
                for (int n = 0; n < 4; ++n) {
                    const int c1 = bnm + wc * 64 + n * 16 + am;
                    const int h = c1 >> 6, d = c1 & 63;
                    const float bv = bias[c1];
                    const size_t hb = ((size_t)(b_ * 16 + h)) << 16;
                    const size_t base = hb + (size_t)(d >> 4) * 16384
                                      + (srow0 >> 5) * 512
                                      + (((srow0 >> 3) & 3) * 16 + (d & 15)) * 8
                                      + (srow0 & 7);
                    u16x4 pk;
                    pk.x = bf16u(acc[m][n][0] + bv);
                    pk.y = bf16u(acc[m][n][1] + bv);
                    pk.z = bf16u(acc[m][n][2] + bv);
                    pk.w = bf16u(acc[m][n][3] + bv);
                    *(u16x4*)&dst[base] = pk;
                }
            }
        } else {
            // Q/K: LDS transpose [c][s] (pad 132), then 16B d-run stores
            __syncthreads();   // staging LDS no longer needed
            #pragma unroll
            for (int m = 0; m < 4; ++m) {
                const int srow = wr * 64 + m * 16 + erow;
                #pragma unroll
                for (int n = 0; n < 4; ++n) {
                    const int ccol = wc * 64 + n * 16 + am;
                    const float bv = bias[bnm + ccol];
                    u16x4 pk;
                    if (tsel == 0) {
                        pk.x = bf16u((acc[m][n][0] + bv) * SCALE_F);
                        pk.y = bf16u((acc[m][n][1] + bv) * SCALE_F);
                        pk.z = bf16u((acc[m][n][2] + bv) * SCALE_F);
                        pk.w = bf16u((acc[m][n][3] + bv) * SCALE_F);
                    } else {
                        pk.x = bf16u(acc[m][n][0] + bv);
                        pk.y = bf16u(acc[m][n][1] + bv);
                        pk.z = bf16u(acc[m][n][2] + bv);
                        pk.w = bf16u(acc[m][n][3] + bv);
                    }
                    *(u16x4*)&shmem[ccol * 132 + srow] = pk;
                }
            }
            __syncthreads();
            #pragma unroll
            for (int j = 0; j < 8; ++j) {
                const int idx = j * 256 + tid;       // 0..2047
                const int s  = idx >> 4;             // 0..127
                const int c8 = idx & 15;             // 8-elem d-run id
                union { ushort_t u[8]; uint4 v; } pk;
                #pragma unroll
                for (int e = 0; e < 8; ++e)
                    pk.u[e] = shmem[(c8 * 8 + e) * 132 + s];
                const int row = bm + s;
                const int b_ = row >> 10;
                const int srow0 = row & 1023;
                const int h = (bnm >> 6) + (c8 >> 3);
                const int d0 = (c8 & 7) * 8;
                const size_t hb = ((size_t)(b_ * 16 + h)) << 16;
                size_t gaddr;
                if (tsel == 0) {
                    gaddr = hb + (size_t)srow0 * 64 + d0;
                } else {
                    gaddr = hb + (size_t)(srow0 >> 4) * 1024
                          + (d0 >> 5) * 512
                          + (((d0 >> 3) & 3) * 16 + (srow0 & 15)) * 8;
                }
                *(uint4*)&dst[gaddr] = pk.v;
            }
        }
    }
}

// ---------------------------------------------------------------------------
// Fused attention v5b: QBLK=16, 4 waves. Swapped QK^T (P in regs; Q is
// pre-scaled by SCALE_F), NO-MAX softmax (clamped exp), 2 barriers total,
// attn nontemporal stores overlapped with PV MFMA, 4-deep V prefetch ring.
// Bijective XCD swizzle keeps each head on one XCD's L2.
// ---------------------------------------------------------------------------
__global__ __launch_bounds__(256, 4) void attn_fused_k(
    const ushort_t* __restrict__ Qh, const ushort_t* __restrict__ Kp,
    const ushort_t* __restrict__ Vp, float* __restrict__ attn,
    ushort_t* __restrict__ ctx)
{
    __shared__ ushort_t Pl[16 * 1024];   // [q][k] bf16, byte^=(q&7)<<4 swizzle
    __shared__ float ssum[4][16];
    __shared__ float invb[16];

    const int tid = threadIdx.x;
    const int lane = tid & 63;
    const int wv = tid >> 6;
    const int am = lane & 15;
    const int ak = lane >> 4;
    const int kb = wv * 256;

    const int wg = blockIdx.x;                    // 16384 blocks
    const int swz = (wg & 7) * 2048 + (wg >> 3);  // bijective XCD swizzle
    const int bh = swz >> 6;
    const int q0 = (swz & 63) << 4;
    const int b = bh >> 4, h = bh & 15;
    const size_t hb = (size_t)bh << 16;           // *65536

    // ---- phase 1: scores^T via mfma(K, Q); lane holds q=am, 64 keys ----
    const ushort_t* qptr = Qh + hb + (size_t)(q0 + am) * 64 + ak * 8;
    const bf16x8 qf0 = *(const bf16x8*)qptr;
    const bf16x8 qf1 = *(const bf16x8*)(qptr + 32);

    f32x4 acc[16];
    #pragma unroll
    for (int n = 0; n < 16; ++n) acc[n] = (f32x4){0.f, 0.f, 0.f, 0.f};

    const ushort_t* kt = Kp + hb + (size_t)(wv * 16) * 1024 + lane * 8;
    __builtin_amdgcn_s_setprio(1);
    #pragma unroll
    for (int n = 0; n < 16; ++n) {
        const bf16x8 kf0 = *(const bf16x8*)(kt + n * 1024);
        const bf16x8 kf1 = *(const bf16x8*)(kt + n * 1024 + 512);
        acc[n] = MFMA16(kf0, qf0, acc[n]);
        acc[n] = MFMA16(kf1, qf1, acc[n]);
    }
    __builtin_amdgcn_s_setprio(0);

    // ---- phase 2: exp (no max pass; Q pre-scaled; arg clamped) ----
    float s = 0.f;
    #pragma unroll
    for (int n = 0; n < 16; ++n)
        #pragma unroll
        for (int r = 0; r < 4; ++r) {
            const float e = __expf(fminf(acc[n][r], 60.0f));
            acc[n][r] = e;
            s += e;
        }
    s += __shfl_xor(s, 16);
    s += __shfl_xor(s, 32);
    if (ak == 0) ssum[wv][am] = s;

    // ---- phase 3a: P (unnormalized e) -> LDS bf16, swizzled ----
    char* prow = (char*)Pl + am * 2048;
    const int xr = (am & 7) << 4;
    #pragma unroll
    for (int n = 0; n < 16; ++n) {
        u16x4 pk;
        pk.x = bf16u(acc[n][0]); pk.y = bf16u(acc[n][1]);
        pk.z = bf16u(acc[n][2]); pk.w = bf16u(acc[n][3]);
        *(u16x4*)(prow + (((kb + n * 16 + ak * 4) * 2) ^ xr)) = pk;
    }
    __syncthreads();   // P + ssum visible

    const float inv = 1.0f / (ssum[0][am] + ssum[1][am] + ssum[2][am] + ssum[3][am]);
    if (wv == 0 && ak == 0) invb[am] = inv;

    // ---- phase 3b: normalized attn from regs (nontemporal, overlaps PV) ----
    float* aout = attn + ((size_t)bh * Ssz + q0 + am) * Ssz + kb + ak * 4;
    #pragma unroll
    for (int n = 0; n < 16; ++n) {
        f32x4 v;
        v[0] = acc[n][0] * inv; v[1] = acc[n][1] * inv;
        v[2] = acc[n][2] * inv; v[3] = acc[n][3] * inv;
        __builtin_nontemporal_store(v, (f32x4*)(aout + n * 16));
    }

    // ---- phase 4: PV. wave wv -> d slice [wv*16,+16); C row q=ak*4+r, col
    //      d=am. 4-deep V prefetch ring; no barrier before (P safe above). ----
    f32x4 po = {0.f, 0.f, 0.f, 0.f};
    const ushort_t* vt = Vp + hb + (size_t)wv * 16384 + lane * 8;
    bf16x8 v0 = *(const bf16x8*)(vt);
    bf16x8 v1 = *(const bf16x8*)(vt + 512);
    bf16x8 v2 = *(const bf16x8*)(vt + 1024);
    bf16x8 v3 = *(const bf16x8*)(vt + 1536);
    __builtin_amdgcn_s_setprio(1);
    #pragma unroll
    for (int w = 0; w < 32; w += 4) {
        const bf16x8 p0 = *(const bf16x8*)(prow + (((w + 0) * 64 + ak * 16) ^ xr));
        const bf16x8 p1 = *(const bf16x8*)(prow + (((w + 1) * 64 + ak * 16) ^ xr));
        const bf16x8 p2 = *(const bf16x8*)(prow + (((w + 2) * 64 + ak * 16) ^ xr));
        const bf16x8 p3 = *(const bf16x8*)(prow + (((w + 3) * 64 + ak * 16) ^ xr));
        po = MFMA16(p0, v0, po);
        if (w + 4 < 32) v0 = *(const bf16x8*)(vt + (w + 4) * 512);
        po = MFMA16(p1, v1, po);
        if (w + 5 < 32) v1 = *(const bf16x8*)(vt + (w + 5) * 512);
        po = MFMA16(p2, v2, po);
        if (w + 6 < 32) v2 = *(const bf16x8*)(vt + (w + 6) * 512);
        po = MFMA16(p3, v3, po);
        if (w + 7 < 32) v3 = *(const bf16x8*)(vt + (w + 7) * 512);
    }
    __builtin_amdgcn_s_setprio(0);
    __syncthreads();   // invb visible

    #pragma unroll
    for (int r = 0; r < 4; ++r) {
        const float v = po[r] * invb[ak * 4 + r];
        ctx[((size_t)b * Ssz + q0 + ak * 4 + r) * Dsz + h * HDs + wv * 16 + am] = bf16u(v);
    }
}

// ---------------------------------------------------------------------------
extern "C" void kernel_launch(void* const* d_in, const int* in_sizes, int n_in,
                              void* d_out, int out_size, void* d_ws, size_t ws_size,
                              hipStream_t stream)
{
    const float* x  = (const float*)d_in[0];
    const float* Wq = (const float*)d_in[1];
    const float* bq = (const float*)d_in[2];
    const float* Wk = (const float*)d_in[3];
    const float* bk = (const float*)d_in[4];
    const float* Wv = (const float*)d_in[5];
    const float* bv = (const float*)d_in[6];
    const float* Wo = (const float*)d_in[7];
    const float* bo = (const float*)d_in[8];

    const size_t BSD = (size_t)Bsz * Ssz * Dsz;   // 16.7M
    const size_t WSZ = (size_t)Dsz * Dsz;         // 1M

    float* outp = (float*)d_out;                  // [B,S,D] fp32
    float* attn = outp + BSD;                     // [B,H,S,S] fp32

    ushort_t* xbf  = (ushort_t*)d_ws;
    ushort_t* Qh   = xbf + BSD;
    ushort_t* Kp   = Qh + BSD;
    ushort_t* Vp   = Kp + BSD;
    ushort_t* ctxb = Vp + BSD;
    ushort_t* Wqkv = ctxb + BSD;                  // [3072][1024] = Wq^T|Wk^T|Wv^T
    ushort_t* Wot  = Wqkv + 3 * WSZ;

    const int M = Bsz * Ssz;                      // 16384

    cast_k<<<dim3((unsigned)(BSD / 2048)), 256, 0, stream>>>(x, xbf, BSD);

    wtrans_k<<<dim3(32, 32, 4), dim3(32, 8), 0, stream>>>(
        Wq, Wk, Wv, Wo, Wqkv, Wot);

    // fused QKV GEMM: N=3072
    gemm_bt_k<1><<<dim3(24, 128), 256, 0, stream>>>(
        xbf, Wqkv, bq, bk, bv, Qh, Kp, Vp, M, 3072, Dsz);

    attn_fused_k<<<dim3(16384), 256, 0, stream>>>(Qh, Kp, Vp, attn, ctxb);

    gemm_bt_k<0><<<dim3(8, 128), 256, 0, stream>>>(
        ctxb, Wot, bo, nullptr, nullptr, outp, nullptr, nullptr, M, Dsz, Dsz);
}

// Round 9
// 472.323 us; speedup vs baseline: 1.6119x; 1.1484x over previous
//
#include <hip/hip_runtime.h>
#include <hip/hip_bf16.h>
#include <cstddef>

#define Bsz 16
#define Ssz 1024
#define Dsz 1024
#define Hn  16
#define HDs 64
#define SCALE_F 0.125f

typedef unsigned short ushort_t;
typedef __bf16 bf16x8 __attribute__((ext_vector_type(8)));
typedef float f32x4 __attribute__((ext_vector_type(4)));
typedef ushort_t u16x4 __attribute__((ext_vector_type(4)));

#define MFMA16(a, b, c) __builtin_amdgcn_mfma_f32_16x16x32_bf16((a), (b), (c), 0, 0, 0)

__device__ inline ushort_t bf16u(float f) {
    __bf16 h = (__bf16)f;
    return __builtin_bit_cast(ushort_t, h);
}

__device__ inline float bf16f(ushort_t u) {
    return __builtin_bit_cast(float, (unsigned)u << 16);
}

__device__ inline void gld_lds16(const void* g, void* l) {
    __builtin_amdgcn_global_load_lds(
        (const __attribute__((address_space(1))) unsigned int*)g,
        (__attribute__((address_space(3))) unsigned int*)l, 16, 0, 0);
}

// ---------------------------------------------------------------------------
// cast fp32 -> bf16, 8 elems/thread
// ---------------------------------------------------------------------------
__global__ __launch_bounds__(256) void cast_k(const float* __restrict__ in,
                                              ushort_t* __restrict__ o, size_t n)
{
    size_t i = ((size_t)blockIdx.x * 256 + threadIdx.x) * 8;
    if (i >= n) return;
    float4 a = *(const float4*)(in + i);
    float4 b = *(const float4*)(in + i + 4);
    union { ushort_t u[8]; uint4 v; } pk;
    pk.u[0] = bf16u(a.x); pk.u[1] = bf16u(a.y); pk.u[2] = bf16u(a.z); pk.u[3] = bf16u(a.w);
    pk.u[4] = bf16u(b.x); pk.u[5] = bf16u(b.y); pk.u[6] = bf16u(b.z); pk.u[7] = bf16u(b.w);
    *(uint4*)(o + i) = pk.v;
}

// ---------------------------------------------------------------------------
// W[K,N] fp32 -> Wt[N,K] bf16, all 4 weights in one launch (z selects)
// ---------------------------------------------------------------------------
__global__ __launch_bounds__(256) void wtrans_k(
    const float* __restrict__ W0, const float* __restrict__ W1,
    const float* __restrict__ W2, const float* __restrict__ W3,
    ushort_t* __restrict__ T012, ushort_t* __restrict__ T3)
{
    __shared__ float t_[32][33];
    const int tx = threadIdx.x, ty = threadIdx.y;
    const int n0 = blockIdx.x * 32, k0 = blockIdx.y * 32;
    const int z = blockIdx.z;
    const float* W = (z == 0) ? W0 : (z == 1) ? W1 : (z == 2) ? W2 : W3;
    ushort_t* Wt = (z < 3) ? (T012 + (size_t)z * Dsz * Dsz) : T3;
    #pragma unroll
    for (int i = 0; i < 4; ++i)
        t_[ty + i * 8][tx] = W[(size_t)(k0 + ty + i * 8) * Dsz + n0 + tx];
    __syncthreads();
    #pragma unroll
    for (int i = 0; i < 4; ++i)
        Wt[(size_t)(n0 + ty + i * 8) * Dsz + k0 + tx] = bf16u(t_[tx][ty + i * 8]);
}

// ---------------------------------------------------------------------------
// C = A[M,K] * Bt[N,K]^T + bias.  bf16 MFMA, 128x128 tile, BK=32.
// MODE 0: fp32 out [M,N] (final projection)
// MODE 1: fused QKV; N=3072; block-uniform tsel = bn>>10 selects target:
//   Q -> Qh[bh][s][64]   (value pre-scaled by SCALE_F)
//   K -> Kp[bh][s>>4][d>>5][((d>>3)&3)*16+(s&15)][d&7]   (1KB lane-packed)
//   V -> Vp[bh][d>>4][s>>5][((s>>3)&3)*16+(d&15)][s&7]   (1KB lane-packed)
// ---------------------------------------------------------------------------
template <int MODE>
__global__ __launch_bounds__(256) void gemm_bt_k(
    const ushort_t* __restrict__ A, const ushort_t* __restrict__ Bt,
    const float* __restrict__ b0, const float* __restrict__ b1,
    const float* __restrict__ b2,
    void* __restrict__ o0, void* __restrict__ o1, void* __restrict__ o2,
    int M, int N, int K)
{
    __shared__ ushort_t shmem[MODE == 1 ? 128 * 132 : 128 * 64];
    ushort_t* As = shmem;                 // 128*32
    ushort_t* Bs = shmem + 128 * 32;      // 128*32

    const int tid = threadIdx.x;
    const int lane = tid & 63;
    const int wv = tid >> 6;
    const int wr = wv >> 1, wc = wv & 1;
    const int bm = blockIdx.y * 128, bn = blockIdx.x * 128;

    const int srw = tid >> 2;
    const int gc = (tid & 3) ^ ((srw >> 1) & 3);
    const ushort_t* aptr0 = A + (size_t)(bm + srw) * K + gc * 8;
    const ushort_t* aptr1 = A + (size_t)(bm + 64 + srw) * K + gc * 8;
    const ushort_t* bptr0 = Bt + (size_t)(bn + srw) * K + gc * 8;
    const ushort_t* bptr1 = Bt + (size_t)(bn + 64 + srw) * K + gc * 8;
    ushort_t* lA0 = As + tid * 8;
    ushort_t* lA1 = As + 2048 + tid * 8;
    ushort_t* lB0 = Bs + tid * 8;
    ushort_t* lB1 = Bs + 2048 + tid * 8;

    const int am = lane & 15;
    const int rc = lane >> 4;
    const int aslot = rc ^ ((am >> 1) & 3);
    const int rrow_a = wr * 64 + am;
    const int rrow_b = wc * 64 + am;

    f32x4 acc[4][4] = {};

    for (int k0 = 0; k0 < K; k0 += 32) {
        if (k0) __syncthreads();
        gld_lds16(aptr0, lA0); gld_lds16(aptr1, lA1);
        gld_lds16(bptr0, lB0); gld_lds16(bptr1, lB1);
        aptr0 += 32; aptr1 += 32; bptr0 += 32; bptr1 += 32;
        __syncthreads();

        bf16x8 af[4], bfr[4];
        #pragma unroll
        for (int m = 0; m < 4; ++m)
            af[m] = *reinterpret_cast<const bf16x8*>(&As[(rrow_a + m * 16) * 32 + aslot * 8]);
        #pragma unroll
        for (int n = 0; n < 4; ++n)
            bfr[n] = *reinterpret_cast<const bf16x8*>(&Bs[(rrow_b + n * 16) * 32 + aslot * 8]);
        #pragma unroll
        for (int m = 0; m < 4; ++m)
            #pragma unroll
            for (int n = 0; n < 4; ++n)
                acc[m][n] = MFMA16(af[m], bfr[n], acc[m][n]);
    }

    const int erow = rc * 4;

    if constexpr (MODE == 0) {
        float* C = (float*)o0;
        #pragma unroll
        for (int m = 0; m < 4; ++m) {
            #pragma unroll
            for (int n = 0; n < 4; ++n) {
                const int col = bn + wc * 64 + n * 16 + am;
                const float bv = b0[col];
                #pragma unroll
                for (int r = 0; r < 4; ++r) {
                    const int row = bm + wr * 64 + m * 16 + erow + r;
                    C[(size_t)row * N + col] = acc[m][n][r] + bv;
                }
            }
        }
    } else {
        const int tsel = bn >> 10;    // block-uniform (1024 % 128 == 0)
        const float* bias = (tsel == 0) ? b0 : (tsel == 1) ? b1 : b2;
        ushort_t* dst = (ushort_t*)((tsel == 0) ? o0 : (tsel == 1) ? o1 : o2);
        const int bnm = bn & 1023;

        if (tsel == 2) {
            // V: direct s-run stores (8B), layout wants s-contiguous
            #pragma unroll
            for (int m = 0; m < 4; ++m) {
                const int row0 = bm + wr * 64 + m * 16 + erow;
                const int b_ = row0 >> 10;
                const int srow0 = row0 & 1023;
                #pragma unroll
                for (int n = 0; n < 4; ++n) {
                    const int c1 = bnm + wc * 64 + n * 16 + am;
                    const int h = c1 >> 6, d = c1 & 63;
                    const float bv = bias[c1];
                    const size_t hb = ((size_t)(b_ * 16 + h)) << 16;
                    const size_t base = hb + (size_t)(d >> 4) * 16384
                                      + (srow0 >> 5) * 512
                                      + (((srow0 >> 3) & 3) * 16 + (d & 15)) * 8
                                      + (srow0 & 7);
                    u16x4 pk;
                    pk.x = bf16u(acc[m][n][0] + bv);
                    pk.y = bf16u(acc[m][n][1] + bv);
                    pk.z = bf16u(acc[m][n][2] + bv);
                    pk.w = bf16u(acc[m][n][3] + bv);
                    *(u16x4*)&dst[base] = pk;
                }
            }
        } else {
            // Q/K: LDS transpose [c][s] (pad 132), then 16B d-run stores
            __syncthreads();   // staging LDS no longer needed
            #pragma unroll
            for (int m = 0; m < 4; ++m) {
                const int srow = wr * 64 + m * 16 + erow;
                #pragma unroll
                for (int n = 0; n < 4; ++n) {
                    const int ccol = wc * 64 + n * 16 + am;
                    const float bv = bias[bnm + ccol];
                    u16x4 pk;
                    if (tsel == 0) {
                        pk.x = bf16u((acc[m][n][0] + bv) * SCALE_F);
                        pk.y = bf16u((acc[m][n][1] + bv) * SCALE_F);
                        pk.z = bf16u((acc[m][n][2] + bv) * SCALE_F);
                        pk.w = bf16u((acc[m][n][3] + bv) * SCALE_F);
                    } else {
                        pk.x = bf16u(acc[m][n][0] + bv);
                        pk.y = bf16u(acc[m][n][1] + bv);
                        pk.z = bf16u(acc[m][n][2] + bv);
                        pk.w = bf16u(acc[m][n][3] + bv);
                    }
                    *(u16x4*)&shmem[ccol * 132 + srow] = pk;
                }
            }
            __syncthreads();
            #pragma unroll
            for (int j = 0; j < 8; ++j) {
                const int idx = j * 256 + tid;       // 0..2047
                const int s  = idx >> 4;             // 0..127
                const int c8 = idx & 15;             // 8-elem d-run id
                union { ushort_t u[8]; uint4 v; } pk;
                #pragma unroll
                for (int e = 0; e < 8; ++e)
                    pk.u[e] = shmem[(c8 * 8 + e) * 132 + s];
                const int row = bm + s;
                const int b_ = row >> 10;
                const int srow0 = row & 1023;
                const int h = (bnm >> 6) + (c8 >> 3);
                const int d0 = (c8 & 7) * 8;
                const size_t hb = ((size_t)(b_ * 16 + h)) << 16;
                size_t gaddr;
                if (tsel == 0) {
                    gaddr = hb + (size_t)srow0 * 64 + d0;
                } else {
                    gaddr = hb + (size_t)(srow0 >> 4) * 1024
                          + (d0 >> 5) * 512
                          + (((d0 >> 3) & 3) * 16 + (srow0 & 15)) * 8;
                }
                *(uint4*)&dst[gaddr] = pk.v;
            }
        }
    }
}

// ---------------------------------------------------------------------------
// Fused attention v6: QBLK=16, 4 waves. Swapped QK^T (P in regs; Q pre-scaled),
// no-max softmax (clamped exp), ONE barrier, attn written COALESCED from LDS P
// (one full 4KB row per iteration, nontemporal), PV with V prefetch ring
// issued before the write loop, ctx epilogue inv from ssum (no final barrier,
// no NT-store drain on critical path). Bijective XCD swizzle.
// ---------------------------------------------------------------------------
__global__ __launch_bounds__(256, 4) void attn_fused_k(
    const ushort_t* __restrict__ Qh, const ushort_t* __restrict__ Kp,
    const ushort_t* __restrict__ Vp, float* __restrict__ attn,
    ushort_t* __restrict__ ctx)
{
    __shared__ ushort_t Pl[16 * 1024];   // [q][k] bf16, byte^=(q&7)<<4 swizzle
    __shared__ float ssum[4][16];

    const int tid = threadIdx.x;
    const int lane = tid & 63;
    const int wv = tid >> 6;
    const int am = lane & 15;
    const int ak = lane >> 4;
    const int kb = wv * 256;

    const int wg = blockIdx.x;                    // 16384 blocks
    const int swz = (wg & 7) * 2048 + (wg >> 3);  // bijective XCD swizzle
    const int bh = swz >> 6;
    const int q0 = (swz & 63) << 4;
    const int b = bh >> 4, h = bh & 15;
    const size_t hb = (size_t)bh << 16;           // *65536

    // ---- phase 1: scores^T via mfma(K, Q); lane holds q=am, 64 keys ----
    const ushort_t* qptr = Qh + hb + (size_t)(q0 + am) * 64 + ak * 8;
    const bf16x8 qf0 = *(const bf16x8*)qptr;
    const bf16x8 qf1 = *(const bf16x8*)(qptr + 32);

    f32x4 acc[16];
    #pragma unroll
    for (int n = 0; n < 16; ++n) acc[n] = (f32x4){0.f, 0.f, 0.f, 0.f};

    const ushort_t* kt = Kp + hb + (size_t)(wv * 16) * 1024 + lane * 8;
    __builtin_amdgcn_s_setprio(1);
    #pragma unroll
    for (int n = 0; n < 16; ++n) {
        const bf16x8 kf0 = *(const bf16x8*)(kt + n * 1024);
        const bf16x8 kf1 = *(const bf16x8*)(kt + n * 1024 + 512);
        acc[n] = MFMA16(kf0, qf0, acc[n]);
        acc[n] = MFMA16(kf1, qf1, acc[n]);
    }
    __builtin_amdgcn_s_setprio(0);

    // ---- phase 2: exp (no max pass; Q pre-scaled; arg clamped) ----
    float s = 0.f;
    #pragma unroll
    for (int n = 0; n < 16; ++n)
        #pragma unroll
        for (int r = 0; r < 4; ++r) {
            const float e = __expf(fminf(acc[n][r], 60.0f));
            acc[n][r] = e;
            s += e;
        }
    s += __shfl_xor(s, 16);
    s += __shfl_xor(s, 32);
    if (ak == 0) ssum[wv][am] = s;

    // ---- phase 3a: P (unnormalized e) -> LDS bf16, swizzled ----
    char* prow = (char*)Pl + am * 2048;
    const int xr = (am & 7) << 4;
    #pragma unroll
    for (int n = 0; n < 16; ++n) {
        u16x4 pk;
        pk.x = bf16u(acc[n][0]); pk.y = bf16u(acc[n][1]);
        pk.z = bf16u(acc[n][2]); pk.w = bf16u(acc[n][3]);
        *(u16x4*)(prow + (((kb + n * 16 + ak * 4) * 2) ^ xr)) = pk;
    }
    __syncthreads();   // P + ssum visible (the only barrier)

    // ---- issue V prefetch ring before the attn write loop ----
    const ushort_t* vt = Vp + hb + (size_t)wv * 16384 + lane * 8;
    bf16x8 v0 = *(const bf16x8*)(vt);
    bf16x8 v1 = *(const bf16x8*)(vt + 512);
    bf16x8 v2 = *(const bf16x8*)(vt + 1024);
    bf16x8 v3 = *(const bf16x8*)(vt + 1536);

    // ---- phase 3b: attn rows from LDS, fully coalesced (4KB/row/iter, NT) ----
    {
        float* aout = attn + ((size_t)bh * Ssz + q0) * Ssz;
        #pragma unroll
        for (int j = 0; j < 16; ++j) {
            const float invj = 1.0f / (ssum[0][j] + ssum[1][j] +
                                       ssum[2][j] + ssum[3][j]);
            const u16x4 pw = *(const u16x4*)((char*)Pl + j * 2048 +
                                             ((tid * 8) ^ ((j & 7) << 4)));
            f32x4 v;
            v[0] = bf16f(pw.x) * invj; v[1] = bf16f(pw.y) * invj;
            v[2] = bf16f(pw.z) * invj; v[3] = bf16f(pw.w) * invj;
            __builtin_nontemporal_store(v, (f32x4*)(aout + (size_t)j * Ssz + tid * 4));
        }
    }

    // ---- phase 4: PV. wave wv -> d slice [wv*16,+16); C row q=ak*4+r, col
    //      d=am. 4-deep V prefetch ring. ----
    f32x4 po = {0.f, 0.f, 0.f, 0.f};
    __builtin_amdgcn_s_setprio(1);
    #pragma unroll
    for (int w = 0; w < 32; w += 4) {
        const bf16x8 p0 = *(const bf16x8*)(prow + (((w + 0) * 64 + ak * 16) ^ xr));
        const bf16x8 p1 = *(const bf16x8*)(prow + (((w + 1) * 64 + ak * 16) ^ xr));
        const bf16x8 p2 = *(const bf16x8*)(prow + (((w + 2) * 64 + ak * 16) ^ xr));
        const bf16x8 p3 = *(const bf16x8*)(prow + (((w + 3) * 64 + ak * 16) ^ xr));
        po = MFMA16(p0, v0, po);
        if (w + 4 < 32) v0 = *(const bf16x8*)(vt + (w + 4) * 512);
        po = MFMA16(p1, v1, po);
        if (w + 5 < 32) v1 = *(const bf16x8*)(vt + (w + 5) * 512);
        po = MFMA16(p2, v2, po);
        if (w + 6 < 32) v2 = *(const bf16x8*)(vt + (w + 6) * 512);
        po = MFMA16(p3, v3, po);
        if (w + 7 < 32) v3 = *(const bf16x8*)(vt + (w + 7) * 512);
    }
    __builtin_amdgcn_s_setprio(0);

    // ---- ctx epilogue: inv recomputed from ssum (no barrier needed) ----
    #pragma unroll
    for (int r = 0; r < 4; ++r) {
        const int q = ak * 4 + r;
        const float invq = 1.0f / (ssum[0][q] + ssum[1][q] +
                                   ssum[2][q] + ssum[3][q]);
        ctx[((size_t)b * Ssz + q0 + q) * Dsz + h * HDs + wv * 16 + am] =
            bf16u(po[r] * invq);
    }
}

// ---------------------------------------------------------------------------
extern "C" void kernel_launch(void* const* d_in, const int* in_sizes, int n_in,
                              void* d_out, int out_size, void* d_ws, size_t ws_size,
                              hipStream_t stream)
{
    const float* x  = (const float*)d_in[0];
    const float* Wq = (const float*)d_in[1];
    const float* bq = (const float*)d_in[2];
    const float* Wk = (const float*)d_in[3];
    const float* bk = (const float*)d_in[4];
    const float* Wv = (const float*)d_in[5];
    const float* bv = (const float*)d_in[6];
    const float* Wo = (const float*)d_in[7];
    const float* bo = (const float*)d_in[8];

    const size_t BSD = (size_t)Bsz * Ssz * Dsz;   // 16.7M
    const size_t WSZ = (size_t)Dsz * Dsz;         // 1M

    float* outp = (float*)d_out;                  // [B,S,D] fp32
    float* attn = outp + BSD;                     // [B,H,S,S] fp32

    ushort_t* xbf  = (ushort_t*)d_ws;
    ushort_t* Qh   = xbf + BSD;
    ushort_t* Kp   = Qh + BSD;
    ushort_t* Vp   = Kp + BSD;
    ushort_t* ctxb = Vp + BSD;
    ushort_t* Wqkv = ctxb + BSD;                  // [3072][1024] = Wq^T|Wk^T|Wv^T
    ushort_t* Wot  = Wqkv + 3 * WSZ;

    const int M = Bsz * Ssz;                      // 16384

    cast_k<<<dim3((unsigned)(BSD / 2048)), 256, 0, stream>>>(x, xbf, BSD);

    wtrans_k<<<dim3(32, 32, 4), dim3(32, 8), 0, stream>>>(
        Wq, Wk, Wv, Wo, Wqkv, Wot);

    // fused QKV GEMM: N=3072
    gemm_bt_k<1><<<dim3(24, 128), 256, 0, stream>>>(
        xbf, Wqkv, bq, bk, bv, Qh, Kp, Vp, M, 3072, Dsz);

    attn_fused_k<<<dim3(16384), 256, 0, stream>>>(Qh, Kp, Vp, attn, ctxb);

    gemm_bt_k<0><<<dim3(8, 128), 256, 0, stream>>>(
        ctxb, Wot, bo, nullptr, nullptr, outp, nullptr, nullptr, M, Dsz, Dsz);
}

// Round 10
// 467.541 us; speedup vs baseline: 1.6284x; 1.0102x over previous
//
#include <hip/hip_runtime.h>
#include <hip/hip_bf16.h>
#include <cstddef>

#define Bsz 16
#define Ssz 1024
#define Dsz 1024
#define Hn  16
#define HDs 64
#define SCALE_F 0.125f

typedef unsigned short ushort_t;
typedef __bf16 bf16x8 __attribute__((ext_vector_type(8)));
typedef float f32x4 __attribute__((ext_vector_type(4)));
typedef ushort_t u16x4 __attribute__((ext_vector_type(4)));

#define MFMA16(a, b, c) __builtin_amdgcn_mfma_f32_16x16x32_bf16((a), (b), (c), 0, 0, 0)

__device__ inline ushort_t bf16u(float f) {
    __bf16 h = (__bf16)f;
    return __builtin_bit_cast(ushort_t, h);
}

__device__ inline float bf16f(ushort_t u) {
    return __builtin_bit_cast(float, (unsigned)u << 16);
}

__device__ inline void gld_lds16(const void* g, void* l) {
    __builtin_amdgcn_global_load_lds(
        (const __attribute__((address_space(1))) unsigned int*)g,
        (__attribute__((address_space(3))) unsigned int*)l, 16, 0, 0);
}

// ---------------------------------------------------------------------------
// cast fp32 -> bf16, 8 elems/thread
// ---------------------------------------------------------------------------
__global__ __launch_bounds__(256) void cast_k(const float* __restrict__ in,
                                              ushort_t* __restrict__ o, size_t n)
{
    size_t i = ((size_t)blockIdx.x * 256 + threadIdx.x) * 8;
    if (i >= n) return;
    float4 a = *(const float4*)(in + i);
    float4 b = *(const float4*)(in + i + 4);
    union { ushort_t u[8]; uint4 v; } pk;
    pk.u[0] = bf16u(a.x); pk.u[1] = bf16u(a.y); pk.u[2] = bf16u(a.z); pk.u[3] = bf16u(a.w);
    pk.u[4] = bf16u(b.x); pk.u[5] = bf16u(b.y); pk.u[6] = bf16u(b.z); pk.u[7] = bf16u(b.w);
    *(uint4*)(o + i) = pk.v;
}

// ---------------------------------------------------------------------------
// W[K,N] fp32 -> Wt[N,K] bf16, all 4 weights in one launch (z selects)
// ---------------------------------------------------------------------------
__global__ __launch_bounds__(256) void wtrans_k(
    const float* __restrict__ W0, const float* __restrict__ W1,
    const float* __restrict__ W2, const float* __restrict__ W3,
    ushort_t* __restrict__ T012, ushort_t* __restrict__ T3)
{
    __shared__ float t_[32][33];
    const int tx = threadIdx.x, ty = threadIdx.y;
    const int n0 = blockIdx.x * 32, k0 = blockIdx.y * 32;
    const int z = blockIdx.z;
    const float* W = (z == 0) ? W0 : (z == 1) ? W1 : (z == 2) ? W2 : W3;
    ushort_t* Wt = (z < 3) ? (T012 + (size_t)z * Dsz * Dsz) : T3;
    #pragma unroll
    for (int i = 0; i < 4; ++i)
        t_[ty + i * 8][tx] = W[(size_t)(k0 + ty + i * 8) * Dsz + n0 + tx];
    __syncthreads();
    #pragma unroll
    for (int i = 0; i < 4; ++i)
        Wt[(size_t)(n0 + ty + i * 8) * Dsz + k0 + tx] = bf16u(t_[tx][ty + i * 8]);
}

// ---------------------------------------------------------------------------
// C = A[M,K] * Bt[N,K]^T + bias.  bf16 MFMA, 128x128 tile, BK=32.
// MODE 0: fp32 out [M,N] (final projection)
// MODE 1: fused QKV; N=3072; block-uniform tsel = bn>>10 selects target:
//   Q -> Qh[bh][s][64]   (value pre-scaled by SCALE_F)
//   K -> Kp[bh][s>>4][d>>5][((d>>3)&3)*16+(s&15)][d&7]   (1KB lane-packed)
//   V -> Vp[bh][d>>4][s>>5][((s>>3)&3)*16+(d&15)][s&7]   (1KB lane-packed)
// ---------------------------------------------------------------------------
template <int MODE>
__global__ __launch_bounds__(256) void gemm_bt_k(
    const ushort_t* __restrict__ A, const ushort_t* __restrict__ Bt,
    const float* __restrict__ b0, const float* __restrict__ b1,
    const float* __restrict__ b2,
    void* __restrict__ o0, void* __restrict__ o1, void* __restrict__ o2,
    int M, int N, int K)
{
    __shared__ ushort_t shmem[MODE == 1 ? 128 * 132 : 128 * 64];
    ushort_t* As = shmem;                 // 128*32
    ushort_t* Bs = shmem + 128 * 32;      // 128*32

    const int tid = threadIdx.x;
    const int lane = tid & 63;
    const int wv = tid >> 6;
    const int wr = wv >> 1, wc = wv & 1;
    const int bm = blockIdx.y * 128, bn = blockIdx.x * 128;

    const int srw = tid >> 2;
    const int gc = (tid & 3) ^ ((srw >> 1) & 3);
    const ushort_t* aptr0 = A + (size_t)(bm + srw) * K + gc * 8;
    const ushort_t* aptr1 = A + (size_t)(bm + 64 + srw) * K + gc * 8;
    const ushort_t* bptr0 = Bt + (size_t)(bn + srw) * K + gc * 8;
    const ushort_t* bptr1 = Bt + (size_t)(bn + 64 + srw) * K + gc * 8;
    ushort_t* lA0 = As + tid * 8;
    ushort_t* lA1 = As + 2048 + tid * 8;
    ushort_t* lB0 = Bs + tid * 8;
    ushort_t* lB1 = Bs + 2048 + tid * 8;

    const int am = lane & 15;
    const int rc = lane >> 4;
    const int aslot = rc ^ ((am >> 1) & 3);
    const int rrow_a = wr * 64 + am;
    const int rrow_b = wc * 64 + am;

    f32x4 acc[4][4] = {};

    for (int k0 = 0; k0 < K; k0 += 32) {
        if (k0) __syncthreads();
        gld_lds16(aptr0, lA0); gld_lds16(aptr1, lA1);
        gld_lds16(bptr0, lB0); gld_lds16(bptr1, lB1);
        aptr0 += 32; aptr1 += 32; bptr0 += 32; bptr1 += 32;
        __syncthreads();

        bf16x8 af[4], bfr[4];
        #pragma unroll
        for (int m = 0; m < 4; ++m)
            af[m] = *reinterpret_cast<const bf16x8*>(&As[(rrow_a + m * 16) * 32 + aslot * 8]);
        #pragma unroll
        for (int n = 0; n < 4; ++n)
            bfr[n] = *reinterpret_cast<const bf16x8*>(&Bs[(rrow_b + n * 16) * 32 + aslot * 8]);
        #pragma unroll
        for (int m = 0; m < 4; ++m)
            #pragma unroll
            for (int n = 0; n < 4; ++n)
                acc[m][n] = MFMA16(af[m], bfr[n], acc[m][n]);
    }

    const int erow = rc * 4;

    if constexpr (MODE == 0) {
        float* C = (float*)o0;
        #pragma unroll
        for (int m = 0; m < 4; ++m) {
            #pragma unroll
            for (int n = 0; n < 4; ++n) {
                const int col = bn + wc * 64 + n * 16 + am;
                const float bv = b0[col];
                #pragma unroll
                for (int r = 0; r < 4; ++r) {
                    const int row = bm + wr * 64 + m * 16 + erow + r;
                    C[(size_t)row * N + col] = acc[m][n][r] + bv;
                }
            }
        }
    } else {
        const int tsel = bn >> 10;    // block-uniform (1024 % 128 == 0)
        const float* bias = (tsel == 0) ? b0 : (tsel == 1) ? b1 : b2;
        ushort_t* dst = (ushort_t*)((tsel == 0) ? o0 : (tsel == 1) ? o1 : o2);
        const int bnm = bn & 1023;

        if (tsel == 2) {
            // V: direct s-run stores (8B), layout wants s-contiguous
            #pragma unroll
            for (int m = 0; m < 4; ++m) {
                const int row0 = bm + wr * 64 + m * 16 + erow;
                const int b_ = row0 >> 10;
                const int srow0 = row0 & 1023;
                #pragma unroll
                for (int n = 0; n < 4; ++n) {
                    const int c1 = bnm + wc * 64 + n * 16 + am;
                    const int h = c1 >> 6, d = c1 & 63;
                    const float bv = bias[c1];
                    const size_t hb = ((size_t)(b_ * 16 + h)) << 16;
                    const size_t base = hb + (size_t)(d >> 4) * 16384
                                      + (srow0 >> 5) * 512
                                      + (((srow0 >> 3) & 3) * 16 + (d & 15)) * 8
                                      + (srow0 & 7);
                    u16x4 pk;
                    pk.x = bf16u(acc[m][n][0] + bv);
                    pk.y = bf16u(acc[m][n][1] + bv);
                    pk.z = bf16u(acc[m][n][2] + bv);
                    pk.w = bf16u(acc[m][n][3] + bv);
                    *(u16x4*)&dst[base] = pk;
                }
            }
        } else {
            // Q/K: LDS transpose [c][s] (pad 132), then 16B d-run stores
            __syncthreads();   // staging LDS no longer needed
            #pragma unroll
            for (int m = 0; m < 4; ++m) {
                const int srow = wr * 64 + m * 16 + erow;
                #pragma unroll
                for (int n = 0; n < 4; ++n) {
                    const int ccol = wc * 64 + n * 16 + am;
                    const float bv = bias[bnm + ccol];
                    u16x4 pk;
                    if (tsel == 0) {
                        pk.x = bf16u((acc[m][n][0] + bv) * SCALE_F);
                        pk.y = bf16u((acc[m][n][1] + bv) * SCALE_F);
                        pk.z = bf16u((acc[m][n][2] + bv) * SCALE_F);
                        pk.w = bf16u((acc[m][n][3] + bv) * SCALE_F);
                    } else {
                        pk.x = bf16u(acc[m][n][0] + bv);
                        pk.y = bf16u(acc[m][n][1] + bv);
                        pk.z = bf16u(acc[m][n][2] + bv);
                        pk.w = bf16u(acc[m][n][3] + bv);
                    }
                    *(u16x4*)&shmem[ccol * 132 + srow] = pk;
                }
            }
            __syncthreads();
            #pragma unroll
            for (int j = 0; j < 8; ++j) {
                const int idx = j * 256 + tid;       // 0..2047
                const int s  = idx >> 4;             // 0..127
                const int c8 = idx & 15;             // 8-elem d-run id
                union { ushort_t u[8]; uint4 v; } pk;
                #pragma unroll
                for (int e = 0; e < 8; ++e)
                    pk.u[e] = shmem[(c8 * 8 + e) * 132 + s];
                const int row = bm + s;
                const int b_ = row >> 10;
                const int srow0 = row & 1023;
                const int h = (bnm >> 6) + (c8 >> 3);
                const int d0 = (c8 & 7) * 8;
                const size_t hb = ((size_t)(b_ * 16 + h)) << 16;
                size_t gaddr;
                if (tsel == 0) {
                    gaddr = hb + (size_t)srow0 * 64 + d0;
                } else {
                    gaddr = hb + (size_t)(srow0 >> 4) * 1024
                          + (d0 >> 5) * 512
                          + (((d0 >> 3) & 3) * 16 + (srow0 & 15) ) * 8;
                }
                *(uint4*)&dst[gaddr] = pk.v;
            }
        }
    }
}

// ---------------------------------------------------------------------------
// Fused attention v7: QBLK=32, 4 waves, 2 q-groups per wave (accA/accB).
// Every K and V fragment feeds TWO MFMAs -> L2 read traffic per q-row halved.
// Swapped QK^T (P in regs; Q pre-scaled), no-max softmax, ONE barrier, attn
// written coalesced from LDS (NT), shared V prefetch ring, ctx inv from ssum.
// Bijective XCD swizzle.
// ---------------------------------------------------------------------------
__global__ __launch_bounds__(256, 2) void attn_fused_k(
    const ushort_t* __restrict__ Qh, const ushort_t* __restrict__ Kp,
    const ushort_t* __restrict__ Vp, float* __restrict__ attn,
    ushort_t* __restrict__ ctx)
{
    __shared__ ushort_t Pl[32 * 1024];   // [q][k] bf16, byte^=(q&7)<<4 swizzle
    __shared__ float ssum[4][32];

    const int tid = threadIdx.x;
    const int lane = tid & 63;
    const int wv = tid >> 6;        // key-slice (QK) and d-slice (PV)
    const int am = lane & 15;
    const int ak = lane >> 4;

    const int wg = blockIdx.x;                    // 8192 blocks
    const int swz = (wg & 7) * 1024 + (wg >> 3);  // bijective XCD swizzle
    const int bh = swz >> 5;
    const int q0 = (swz & 31) << 5;
    const int b = bh >> 4, h = bh & 15;
    const size_t hb = (size_t)bh << 16;           // *65536

    // ---- phase 1: scores^T via mfma(K, Q) for BOTH q-groups ----
    const ushort_t* qptrA = Qh + hb + (size_t)(q0 + am) * 64 + ak * 8;
    const bf16x8 qfA0 = *(const bf16x8*)qptrA;
    const bf16x8 qfA1 = *(const bf16x8*)(qptrA + 32);
    const bf16x8 qfB0 = *(const bf16x8*)(qptrA + 16 * 64);
    const bf16x8 qfB1 = *(const bf16x8*)(qptrA + 16 * 64 + 32);

    f32x4 accA[16], accB[16];
    #pragma unroll
    for (int n = 0; n < 16; ++n) {
        accA[n] = (f32x4){0.f, 0.f, 0.f, 0.f};
        accB[n] = (f32x4){0.f, 0.f, 0.f, 0.f};
    }

    const ushort_t* kt = Kp + hb + (size_t)(wv * 16) * 1024 + lane * 8;
    __builtin_amdgcn_s_setprio(1);
    #pragma unroll
    for (int n = 0; n < 16; ++n) {
        const bf16x8 kf0 = *(const bf16x8*)(kt + n * 1024);
        const bf16x8 kf1 = *(const bf16x8*)(kt + n * 1024 + 512);
        accA[n] = MFMA16(kf0, qfA0, accA[n]);
        accA[n] = MFMA16(kf1, qfA1, accA[n]);
        accB[n] = MFMA16(kf0, qfB0, accB[n]);
        accB[n] = MFMA16(kf1, qfB1, accB[n]);
    }
    __builtin_amdgcn_s_setprio(0);

    // ---- phase 2: exp (no max pass; Q pre-scaled; arg clamped) ----
    float sA = 0.f, sB = 0.f;
    #pragma unroll
    for (int n = 0; n < 16; ++n)
        #pragma unroll
        for (int r = 0; r < 4; ++r) {
            const float eA = __expf(fminf(accA[n][r], 60.0f));
            accA[n][r] = eA; sA += eA;
            const float eB = __expf(fminf(accB[n][r], 60.0f));
            accB[n][r] = eB; sB += eB;
        }
    sA += __shfl_xor(sA, 16); sA += __shfl_xor(sA, 32);
    sB += __shfl_xor(sB, 16); sB += __shfl_xor(sB, 32);
    if (ak == 0) { ssum[wv][am] = sA; ssum[wv][16 + am] = sB; }

    // ---- phase 3a: P (unnormalized e) -> LDS bf16, swizzled ----
    const int kb = wv * 256;
    char* prowA = (char*)Pl + am * 2048;
    char* prowB = (char*)Pl + (16 + am) * 2048;
    const int xr = (am & 7) << 4;                 // same for rows am, 16+am
    #pragma unroll
    for (int n = 0; n < 16; ++n) {
        const int off = ((kb + n * 16 + ak * 4) * 2) ^ xr;
        u16x4 pa, pb;
        pa.x = bf16u(accA[n][0]); pa.y = bf16u(accA[n][1]);
        pa.z = bf16u(accA[n][2]); pa.w = bf16u(accA[n][3]);
        pb.x = bf16u(accB[n][0]); pb.y = bf16u(accB[n][1]);
        pb.z = bf16u(accB[n][2]); pb.w = bf16u(accB[n][3]);
        *(u16x4*)(prowA + off) = pa;
        *(u16x4*)(prowB + off) = pb;
    }
    __syncthreads();   // P + ssum visible (the only barrier)

    // ---- issue V prefetch ring before the attn write loop ----
    const ushort_t* vt = Vp + hb + (size_t)wv * 16384 + lane * 8;
    bf16x8 v0 = *(const bf16x8*)(vt);
    bf16x8 v1 = *(const bf16x8*)(vt + 512);
    bf16x8 v2 = *(const bf16x8*)(vt + 1024);
    bf16x8 v3 = *(const bf16x8*)(vt + 1536);

    // ---- phase 3b: attn rows from LDS, fully coalesced (4KB/row/iter, NT) ----
    {
        float* aout = attn + ((size_t)bh * Ssz + q0) * Ssz;
        #pragma unroll
        for (int j = 0; j < 32; ++j) {
            const float invj = 1.0f / (ssum[0][j] + ssum[1][j] +
                                       ssum[2][j] + ssum[3][j]);
            const u16x4 pw = *(const u16x4*)((char*)Pl + j * 2048 +
                                             ((tid * 8) ^ ((j & 7) << 4)));
            f32x4 v;
            v[0] = bf16f(pw.x) * invj; v[1] = bf16f(pw.y) * invj;
            v[2] = bf16f(pw.z) * invj; v[3] = bf16f(pw.w) * invj;
            __builtin_nontemporal_store(v, (f32x4*)(aout + (size_t)j * Ssz + tid * 4));
        }
    }

    // ---- phase 4: PV for both q-groups; V fragment shared. wave wv ->
    //      d slice [wv*16,+16); C row q = g*16 + ak*4+r, col d = am. ----
    f32x4 poA = {0.f, 0.f, 0.f, 0.f};
    f32x4 poB = {0.f, 0.f, 0.f, 0.f};
    __builtin_amdgcn_s_setprio(1);
    #pragma unroll
    for (int w = 0; w < 32; w += 4) {
        const int o0 = ((w + 0) * 64 + ak * 16) ^ xr;
        const int o1 = ((w + 1) * 64 + ak * 16) ^ xr;
        const int o2 = ((w + 2) * 64 + ak * 16) ^ xr;
        const int o3 = ((w + 3) * 64 + ak * 16) ^ xr;
        poA = MFMA16(*(const bf16x8*)(prowA + o0), v0, poA);
        poB = MFMA16(*(const bf16x8*)(prowB + o0), v0, poB);
        if (w + 4 < 32) v0 = *(const bf16x8*)(vt + (w + 4) * 512);
        poA = MFMA16(*(const bf16x8*)(prowA + o1), v1, poA);
        poB = MFMA16(*(const bf16x8*)(prowB + o1), v1, poB);
        if (w + 5 < 32) v1 = *(const bf16x8*)(vt + (w + 5) * 512);
        poA = MFMA16(*(const bf16x8*)(prowA + o2), v2, poA);
        poB = MFMA16(*(const bf16x8*)(prowB + o2), v2, poB);
        if (w + 6 < 32) v2 = *(const bf16x8*)(vt + (w + 6) * 512);
        poA = MFMA16(*(const bf16x8*)(prowA + o3), v3, poA);
        poB = MFMA16(*(const bf16x8*)(prowB + o3), v3, poB);
        if (w + 7 < 32) v3 = *(const bf16x8*)(vt + (w + 7) * 512);
    }
    __builtin_amdgcn_s_setprio(0);

    // ---- ctx epilogue: inv recomputed from ssum (no barrier needed) ----
    #pragma unroll
    for (int r = 0; r < 4; ++r) {
        const int qA = ak * 4 + r;
        const float invA = 1.0f / (ssum[0][qA] + ssum[1][qA] +
                                   ssum[2][qA] + ssum[3][qA]);
        ctx[((size_t)b * Ssz + q0 + qA) * Dsz + h * HDs + wv * 16 + am] =
            bf16u(poA[r] * invA);
        const int qB = 16 + qA;
        const float invB = 1.0f / (ssum[0][qB] + ssum[1][qB] +
                                   ssum[2][qB] + ssum[3][qB]);
        ctx[((size_t)b * Ssz + q0 + qB) * Dsz + h * HDs + wv * 16 + am] =
            bf16u(poB[r] * invB);
    }
}

// ---------------------------------------------------------------------------
extern "C" void kernel_launch(void* const* d_in, const int* in_sizes, int n_in,
                              void* d_out, int out_size, void* d_ws, size_t ws_size,
                              hipStream_t stream)
{
    const float* x  = (const float*)d_in[0];
    const float* Wq = (const float*)d_in[1];
    const float* bq = (const float*)d_in[2];
    const float* Wk = (const float*)d_in[3];
    const float* bk = (const float*)d_in[4];
    const float* Wv = (const float*)d_in[5];
    const float* bv = (const float*)d_in[6];
    const float* Wo = (const float*)d_in[7];
    const float* bo = (const float*)d_in[8];

    const size_t BSD = (size_t)Bsz * Ssz * Dsz;   // 16.7M
    const size_t WSZ = (size_t)Dsz * Dsz;         // 1M

    float* outp = (float*)d_out;                  // [B,S,D] fp32
    float* attn = outp + BSD;                     // [B,H,S,S] fp32

    ushort_t* xbf  = (ushort_t*)d_ws;
    ushort_t* Qh   = xbf + BSD;
    ushort_t* Kp   = Qh + BSD;
    ushort_t* Vp   = Kp + BSD;
    ushort_t* ctxb = Vp + BSD;
    ushort_t* Wqkv = ctxb + BSD;                  // [3072][1024] = Wq^T|Wk^T|Wv^T
    ushort_t* Wot  = Wqkv + 3 * WSZ;

    const int M = Bsz * Ssz;                      // 16384

    cast_k<<<dim3((unsigned)(BSD / 2048)), 256, 0, stream>>>(x, xbf, BSD);

    wtrans_k<<<dim3(32, 32, 4), dim3(32, 8), 0, stream>>>(
        Wq, Wk, Wv, Wo, Wqkv, Wot);

    // fused QKV GEMM: N=3072
    gemm_bt_k<1><<<dim3(24, 128), 256, 0, stream>>>(
        xbf, Wqkv, bq, bk, bv, Qh, Kp, Vp, M, 3072, Dsz);

    attn_fused_k<<<dim3(8192), 256, 0, stream>>>(Qh, Kp, Vp, attn, ctxb);

    gemm_bt_k<0><<<dim3(8, 128), 256, 0, stream>>>(
        ctxb, Wot, bo, nullptr, nullptr, outp, nullptr, nullptr, M, Dsz, Dsz);
}